// Round 2
// 470.420 us; speedup vs baseline: 1.0437x; 1.0437x over previous
//
#include <hip/hip_runtime.h>
#include <math.h>

#define BATCH 512
#define NEG_BIG (-3.0e38f)

typedef __attribute__((ext_vector_type(8))) short short8;
typedef __attribute__((ext_vector_type(4))) float floatx4;

// pack two fp32 into two bf16 (truncation) with one v_perm
__device__ inline unsigned pk2(float lo, float hi) {
    return __builtin_amdgcn_perm(__float_as_uint(hi), __float_as_uint(lo), 0x07060302u);
}
__device__ inline short8 cvt8(float4 a, float4 b) {
    union { unsigned u[4]; short8 s; } r;
    r.u[0] = pk2(a.x, a.y); r.u[1] = pk2(a.z, a.w);
    r.u[2] = pk2(b.x, b.y); r.u[3] = pk2(b.z, b.w);
    return r.s;
}
// RNE fp32->bf16
__device__ inline short f2bf(float f) {
    unsigned u = __float_as_uint(f);
    u += 0x7FFFu + ((u >> 16) & 1u);
    return (short)(u >> 16);
}
__device__ inline float bf2f(short s) {
    return __uint_as_float(((unsigned)(unsigned short)s) << 16);
}

// ---------------------------------------------------------------------------
// Combined weight prep (one dispatch). Wt[n][k_off+k] = bf16(W[k][n]).
// ---------------------------------------------------------------------------
__device__ inline void wprep_body(
    const float* __restrict__ W, int K, int N,
    short* __restrict__ Wt, int KP, int k_off,
    int lid, int kbt, float (*tile)[33])
{
    const int kb = (lid % kbt) * 32, nb = (lid / kbt) * 32;
    const int c = threadIdx.x & 31, r0 = threadIdx.x >> 5;
    #pragma unroll
    for (int i = 0; i < 4; ++i) {
        const int r = r0 + i * 8;
        const int k = kb + r;
        tile[r][c] = (k < K) ? W[(size_t)k * N + nb + c] : 0.f;
    }
    __syncthreads();
    #pragma unroll
    for (int i = 0; i < 4; ++i) {
        const int n = nb + r0 + i * 8;
        Wt[(size_t)n * KP + k_off + kb + c] = f2bf(tile[c][r0 + i * 8]);
    }
}

__global__ __launch_bounds__(256) void k_wprep_all(
    const float* __restrict__ W_ms, const float* __restrict__ W_item,
    const float* __restrict__ W_ab, const float* __restrict__ W_user,
    const float* __restrict__ W_mo1, const float* __restrict__ W_so1,
    short* __restrict__ Wt_pre, short* __restrict__ Wt_user,
    short* __restrict__ Wt_mo, short* __restrict__ Wt_mv,
    short* __restrict__ Wt_so, short* __restrict__ Wt_sw)
{
    __shared__ float tile[32][33];
    const int l = blockIdx.x;
    if      (l < 68)   wprep_body(W_ms,   516,  128, Wt_pre,  1056, 0,   l,        17, tile);
    else if (l < 100)  wprep_body(W_item, 256,  128, Wt_pre,  1056, 544, l - 68,   8,  tile);
    else if (l < 132)  wprep_body(W_ab,   256,  128, Wt_pre,  1056, 800, l - 100,  8,  tile);
    else if (l < 788)  wprep_body(W_user, 1281, 512, Wt_user, 1312, 0,   l - 132,  41, tile);
    else if (l < 1844) wprep_body(W_mo1,  2091, 512, Wt_mo,   2112, 0,   l - 788,  66, tile);
    else if (l < 1908) wprep_body(W_mo1 + (size_t)2091 * 512, 128, 512, Wt_mv, 128, 0, l - 1844, 4, tile);
    else if (l < 2964) wprep_body(W_so1,  2091, 512, Wt_so,   2112, 0,   l - 1908, 66, tile);
    else               wprep_body(W_so1 + (size_t)2091 * 512, 512, 512, Wt_sw, 512, 0, l - 2964, 16, tile);
}

// ---------------------------------------------------------------------------
// Pre-layer fused GEMM.
//  - Staging: two-phase, register-batched (23 float4 loads in flight per
//    thread before any LDS write) -> deep VMEM pipelining.
//  - Compute: 4-deep B register ring (fully unrolled, compile-time slots).
// LDS layout (shorts):
//   sA(b,r,c) = S[(b*17+r)*552 + c], r: 0-3 moveset, 4-11 movepool, 12-16 lookup
//               cols [516,544) zeroed (K-pad); stride 552 breaks bank aliasing.
//   sI(b,r,c) = S[18768 + (b*5+r)*264 + c], r: 0-1 items, 2 berry, 3-4 abilities
// ---------------------------------------------------------------------------
#define STRA 552
#define SIOFF 18768
#define STRI 264
#define ZEROE 528

__device__ inline void stage4(short* S, int e, float4 v) {
    uint2 wv; wv.x = pk2(v.x, v.y); wv.y = pk2(v.z, v.w);
    *(uint2*)(S + e) = wv;
}

__global__ __launch_bounds__(256, 3) void k_pre_gemm(
    const float* __restrict__ moveset, const float* __restrict__ movepool,
    const float* __restrict__ lookup,  const float* __restrict__ items,
    const float* __restrict__ lastberry, const float* __restrict__ abilities,
    const float* __restrict__ lookup_mask, const float* __restrict__ berry_mask,
    const float* __restrict__ user_x, const float* __restrict__ types_x,
    const float* __restrict__ tera_types,
    const short* __restrict__ Wt,   // [128][1056] bf16
    const float* __restrict__ b_ms, const float* __restrict__ b_item,
    const float* __restrict__ b_ab,
    short* __restrict__ u_in)       // [6144][1312] bf16
{
    __shared__ __align__(16) short S[21408];   // 42.8 KB; ec (25 KB) aliases after barrier
    const int t = threadIdx.x;
    const int bsu0 = blockIdx.x * 2;

    // ---- stage A into LDS: phase 1 = issue ALL loads (clamped duplicate
    // indices keep trip counts compile-time; dup LDS writes are same-value,
    // benign), phase 2 = convert + ds_write. ----
    {
        const float4* msrc = (const float4*)(moveset + (size_t)bsu0 * 4 * 516);
        const float4* psrc = (const float4*)(movepool + (size_t)bsu0 * 8 * 516);
        const float4* lsrc = (const float4*)(lookup + (size_t)bsu0 * 5 * 516);
        const float4* isrc = (const float4*)(items + (size_t)bsu0 * 2 * 256);
        const float4* bsrc = (const float4*)(lastberry + (size_t)bsu0 * 256);
        const float4* asrc = (const float4*)(abilities + (size_t)bsu0 * 2 * 256);

        float4 rm[5], rp[9], rl[6], rit, rlb, rab;
        #pragma unroll
        for (int j = 0; j < 5; ++j) {
            int i = t + j * 256; if (i > 1031) i = 1031;
            rm[j] = msrc[i];
        }
        #pragma unroll
        for (int j = 0; j < 9; ++j) {
            int i = t + j * 256; if (i > 2063) i = 2063;
            rp[j] = psrc[i];
        }
        #pragma unroll
        for (int j = 0; j < 6; ++j) {
            int i = t + j * 256; if (i > 1289) i = 1289;
            rl[j] = lsrc[i];
        }
        rit = isrc[t];
        rlb = bsrc[t & 127];
        rab = asrc[t];

        // phase 2: writes (vmcnt waits amortize across 23 in-flight loads)
        #pragma unroll
        for (int j = 0; j < 5; ++j) {
            int i = t + j * 256; if (i > 1031) i = 1031;
            const int g = i / 129, jj = i - g * 129;
            stage4(S, ((g >> 2) * 17 + (g & 3)) * STRA + jj * 4, rm[j]);
        }
        #pragma unroll
        for (int j = 0; j < 9; ++j) {
            int i = t + j * 256; if (i > 2063) i = 2063;
            const int g = i / 129, jj = i - g * 129;
            stage4(S, ((g >> 3) * 17 + 4 + (g & 7)) * STRA + jj * 4, rp[j]);
        }
        #pragma unroll
        for (int j = 0; j < 6; ++j) {
            int i = t + j * 256; if (i > 1289) i = 1289;
            const int g = i / 129, jj = i - g * 129;
            const int b = g / 5, r = g - b * 5;
            stage4(S, (b * 17 + 12 + r) * STRA + jj * 4, rl[j]);
        }
        {
            const int g = t >> 6, j = t & 63;
            stage4(S, SIOFF + ((g >> 1) * 5 + (g & 1)) * STRI + j * 4, rit);
        }
        {
            const int i = t & 127, g = i >> 6, j = i & 63;
            stage4(S, SIOFF + (g * 5 + 2) * STRI + j * 4, rlb);
        }
        {
            const int g = t >> 6, j = t & 63;
            stage4(S, SIOFF + ((g >> 1) * 5 + 3 + (g & 1)) * STRI + j * 4, rab);
        }
        // zero K-pad cols [516,544) of the 34 sA rows
        #pragma unroll
        for (int j = 0; j < 2; ++j) {
            const int i = t + j * 256;
            if (i < 476) {
                const int rr = i / 14, p = i - rr * 14;
                *(unsigned*)(S + rr * STRA + 516 + p * 2) = 0u;
            }
        }
    }
    __syncthreads();

    // ---- compute ----
    const int lane = t & 63, w = t >> 6;
    const int m = lane & 15, q = lane >> 4;

    // T2 lane setup: branchless per-step source (zero block when out of window)
    int t2base = ZEROE, t2lo = 1, t2hi = 0;
    {
        int jj = m, b = 0;
        if (m >= 6 && m < 12) { b = 1; jj = m - 6; }
        if (m < 12) {
            if (jj == 0)      { t2base = (b * 17 + 16) * STRA;             t2lo = 0;  t2hi = 16; }
            else if (jj <= 2) { t2base = SIOFF + (b * 5 + (jj - 1)) * STRI; t2lo = 17; t2hi = 24; }
            else if (jj == 3) { t2base = SIOFF + (b * 5 + 2) * STRI;        t2lo = 17; t2hi = 24; }
            else              { t2base = SIOFF + (b * 5 + 3 + (jj - 4)) * STRI; t2lo = 25; t2hi = 32; }
        }
    }
    const short* bp0 = Wt + (size_t)(w * 32 + m) * 1056 + q * 8;
    const short* bp1 = bp0 + (size_t)16 * 1056;

    floatx4 acc[3][2];
    #pragma unroll
    for (int i = 0; i < 3; ++i) {
        acc[i][0] = (floatx4){0.f, 0.f, 0.f, 0.f};
        acc[i][1] = (floatx4){0.f, 0.f, 0.f, 0.f};
    }

    // 4-deep B register ring (slot d holds step s with s%4==d)
    short8 B0[4], B1[4];
    #pragma unroll
    for (int d = 0; d < 4; ++d) {
        B0[d] = *(const short8*)(bp0 + d * 32);
        B1[d] = *(const short8*)(bp1 + d * 32);
    }
    const int aoff = q * 8;

    // part 1: s = 0..16 (T0, T1, T2)
    #pragma unroll
    for (int s = 0; s <= 16; ++s) {
        const int k0 = s * 32 + aoff;
        short8 a0 = *(const short8*)(S + m * STRA + k0);
        short8 a1 = *(const short8*)(S + (17 + m) * STRA + k0);
        const int e2 = (s >= t2lo && s <= t2hi) ? t2base + (s - t2lo) * 32 + aoff : ZEROE;
        short8 a2 = *(const short8*)(S + e2);
        acc[0][0] = __builtin_amdgcn_mfma_f32_16x16x32_bf16(a0, B0[s & 3], acc[0][0], 0, 0, 0);
        acc[0][1] = __builtin_amdgcn_mfma_f32_16x16x32_bf16(a0, B1[s & 3], acc[0][1], 0, 0, 0);
        acc[1][0] = __builtin_amdgcn_mfma_f32_16x16x32_bf16(a1, B0[s & 3], acc[1][0], 0, 0, 0);
        acc[1][1] = __builtin_amdgcn_mfma_f32_16x16x32_bf16(a1, B1[s & 3], acc[1][1], 0, 0, 0);
        acc[2][0] = __builtin_amdgcn_mfma_f32_16x16x32_bf16(a2, B0[s & 3], acc[2][0], 0, 0, 0);
        acc[2][1] = __builtin_amdgcn_mfma_f32_16x16x32_bf16(a2, B1[s & 3], acc[2][1], 0, 0, 0);
        if (s + 4 <= 32) {   // compile-time after unroll
            B0[s & 3] = *(const short8*)(bp0 + (s + 4) * 32);
            B1[s & 3] = *(const short8*)(bp1 + (s + 4) * 32);
        }
    }
    // part 2: s = 17..32 (T2 only)
    #pragma unroll
    for (int s = 17; s <= 32; ++s) {
        const int e2 = (s >= t2lo && s <= t2hi) ? t2base + (s - t2lo) * 32 + aoff : ZEROE;
        short8 a2 = *(const short8*)(S + e2);
        acc[2][0] = __builtin_amdgcn_mfma_f32_16x16x32_bf16(a2, B0[s & 3], acc[2][0], 0, 0, 0);
        acc[2][1] = __builtin_amdgcn_mfma_f32_16x16x32_bf16(a2, B1[s & 3], acc[2][1], 0, 0, 0);
        if (s + 4 <= 32) {
            B0[s & 3] = *(const short8*)(bp0 + (s + 4) * 32);
            B1[s & 3] = *(const short8*)(bp1 + (s + 4) * 32);
        }
    }

    __syncthreads();   // A reads done before ec overwrites S
    float* ec = (float*)S;   // 128*49 floats

    #pragma unroll
    for (int nt = 0; nt < 2; ++nt) {
        const int col = w * 32 + nt * 16 + m;
        #pragma unroll
        for (int r = 0; r < 4; ++r) {
            const int row = q * 4 + r;   // D: row = quad*4 + reg
            ec[col * 49 + row]      = acc[0][nt][r];
            ec[col * 49 + 24 + row] = acc[1][nt][r];
            if (row < 6)            ec[col * 49 + 16 + row]            = acc[2][nt][r];
            else if (row < 12)      ec[col * 49 + 24 + 16 + (row - 6)] = acc[2][nt][r];
        }
    }
    __syncthreads();
    {
        const int c  = t & 127;
        const int bi = t >> 7;
        const int bsu = bsu0 + bi;
        const float* v = &ec[c * 49 + bi * 24];
        short* __restrict__ orow = u_in + (size_t)bsu * 1312;
        const float bms = b_ms[c], bit = b_item[c], bab = b_ab[c];
        float msx = 0.f;
        #pragma unroll
        for (int r = 0; r < 4; ++r) msx = fmaxf(msx, v[r] + bms);
        float pool = 0.f;
        #pragma unroll
        for (int r = 4; r < 12; ++r) pool += fmaxf(v[r] + bms, 0.f);
        pool *= 0.125f;
        orow[857 + c] = f2bf(fmaxf(msx, pool));
        #pragma unroll
        for (int sl = 0; sl < 5; ++sl) {
            const float mask = lookup_mask[bsu * 5 + sl];
            orow[89 + sl * 128 + c] = f2bf(fmaxf(v[12 + sl] + bms, 0.f) * mask);
        }
        orow[985 + c]  = f2bf(0.5f * (fmaxf(v[17] + bit, 0.f) + fmaxf(v[18] + bit, 0.f)));
        orow[729 + c]  = f2bf(fmaxf(v[19] + bit, 0.f) * berry_mask[bsu]);
        orow[1113 + c] = f2bf(0.5f * (fmaxf(v[20] + bab, 0.f) + fmaxf(v[21] + bab, 0.f)));
        if (c < 89) orow[c] = f2bf(user_x[(size_t)bsu * 89 + c]);
        if (c < 20) {
            orow[1241 + c] = f2bf(types_x[bsu * 20 + c]);
            orow[1261 + c] = f2bf(tera_types[bsu * 20 + c]);
        }
        if (c < 31) orow[1281 + c] = 0;
    }
}

// ---------------------------------------------------------------------------
// Generic MFMA GEMM, 4-deep register-ring pipeline (A and B), M-tile 32,
// optional split-K over blockIdx.z.  Requires ksteps >= 4.
// ---------------------------------------------------------------------------
template<int AMODE, bool ABF16, bool RELU, bool HASBIAS, bool OBF16>
__global__ __launch_bounds__(256, 3) void k_gemm(
    const void* __restrict__ Av, int strideA,
    const void* __restrict__ gbasev, const int* __restrict__ gidx,
    const short* __restrict__ Wt, int KP,
    const float* __restrict__ bias,
    void* __restrict__ Cv, size_t partStride, int ksteps)
{
    const int t = threadIdx.x, lane = t & 63, w = t >> 6;
    const int m = lane & 15, q = lane >> 4;
    const int mb = blockIdx.x * 32;
    const int nb = blockIdx.y * 128 + w * 32;
    const int z = blockIdx.z;
    const int koff = z * ksteps * 32;

    const short* aps[2]; const float* apf[2];
    #pragma unroll
    for (int i = 0; i < 2; ++i) {
        const int row = mb + i * 16 + m;
        size_t roff;
        if (AMODE == 0) roff = (size_t)row * strideA;
        else {
            const int bb = row / 6, j = row - bb * 6;
            roff = ((size_t)bb * 12 + gidx[bb * 6 + j]) * 512;
        }
        if (ABF16) aps[i] = (const short*)Av + roff + koff + q * 8;
        else       apf[i] = (const float*)Av + roff + koff + q * 8;
        if (AMODE == 1) aps[i] = (const short*)gbasev + roff + koff + q * 8;
    }
    const short* bp0 = Wt + (size_t)(nb + m) * KP + koff + q * 8;
    const short* bp1 = bp0 + (size_t)16 * KP;

    floatx4 acc[2][2];
    #pragma unroll
    for (int i = 0; i < 2; ++i) {
        acc[i][0] = (floatx4){0.f, 0.f, 0.f, 0.f};
        acc[i][1] = (floatx4){0.f, 0.f, 0.f, 0.f};
    }

    // 4-deep rings; slot d holds k-step s with s%4==d (compile-time indices)
    short8 Ab[4][2];
    float4 Af[4][2][2];
    short8 B0b[4], B1b[4];
    #pragma unroll
    for (int d = 0; d < 4; ++d) {
        #pragma unroll
        for (int i = 0; i < 2; ++i) {
            if (ABF16) Ab[d][i] = *(const short8*)(aps[i] + d * 32);
            else {
                Af[d][i][0] = *(const float4*)(apf[i] + d * 32);
                Af[d][i][1] = *(const float4*)(apf[i] + d * 32 + 4);
            }
        }
        B0b[d] = *(const short8*)(bp0 + d * 32);
        B1b[d] = *(const short8*)(bp1 + d * 32);
    }

    int s = 0;
    for (; s + 4 < ksteps; s += 4) {
        #pragma unroll
        for (int d = 0; d < 4; ++d) {
            #pragma unroll
            for (int i = 0; i < 2; ++i) {
                const short8 av = ABF16 ? Ab[d][i] : cvt8(Af[d][i][0], Af[d][i][1]);
                acc[i][0] = __builtin_amdgcn_mfma_f32_16x16x32_bf16(av, B0b[d], acc[i][0], 0, 0, 0);
                acc[i][1] = __builtin_amdgcn_mfma_f32_16x16x32_bf16(av, B1b[d], acc[i][1], 0, 0, 0);
            }
            int ns = s + d + 4; if (ns > ksteps - 1) ns = ksteps - 1;  // clamp dup, never consumed
            const int o = ns * 32;
            #pragma unroll
            for (int i = 0; i < 2; ++i) {
                if (ABF16) Ab[d][i] = *(const short8*)(aps[i] + o);
                else {
                    Af[d][i][0] = *(const float4*)(apf[i] + o);
                    Af[d][i][1] = *(const float4*)(apf[i] + o + 4);
                }
            }
            B0b[d] = *(const short8*)(bp0 + o);
            B1b[d] = *(const short8*)(bp1 + o);
        }
    }
    // tail: steps s..ksteps-1 (1..4 of them); s%4==0 so slot d == step s+d
    #pragma unroll
    for (int d = 0; d < 4; ++d) {
        if (s + d < ksteps) {
            #pragma unroll
            for (int i = 0; i < 2; ++i) {
                const short8 av = ABF16 ? Ab[d][i] : cvt8(Af[d][i][0], Af[d][i][1]);
                acc[i][0] = __builtin_amdgcn_mfma_f32_16x16x32_bf16(av, B0b[d], acc[i][0], 0, 0, 0);
                acc[i][1] = __builtin_amdgcn_mfma_f32_16x16x32_bf16(av, B1b[d], acc[i][1], 0, 0, 0);
            }
        }
    }

    const float bb0 = (HASBIAS && z == 0) ? bias[nb + m] : 0.f;
    const float bb1 = (HASBIAS && z == 0) ? bias[nb + 16 + m] : 0.f;
    #pragma unroll
    for (int i = 0; i < 2; ++i) {
        #pragma unroll
        for (int r = 0; r < 4; ++r) {
            const int row = mb + i * 16 + q * 4 + r;
            float v0 = acc[i][0][r] + bb0;
            float v1 = acc[i][1][r] + bb1;
            if (RELU) { v0 = fmaxf(v0, 0.f); v1 = fmaxf(v1, 0.f); }
            if (OBF16) {
                short* C = (short*)Cv + z * partStride;
                C[(size_t)row * 512 + nb + m]      = f2bf(v0);
                C[(size_t)row * 512 + nb + 16 + m] = f2bf(v1);
            } else {
                float* C = (float*)Cv + z * partStride;
                C[(size_t)row * 512 + nb + m]      = v0;
                C[(size_t)row * 512 + nb + 16 + m] = v1;
            }
        }
    }
}

// ---------------------------------------------------------------------------
// battle_full bf16 [B][2112]
// ---------------------------------------------------------------------------
__global__ __launch_bounds__(256) void k_battle(
    const float* __restrict__ battle_x, const float* __restrict__ side_x,
    const short* __restrict__ u, const int* __restrict__ active_idx,
    short* __restrict__ bfb)
{
    const int b = blockIdx.x;
    const int t = threadIdx.x;
    short* __restrict__ o = bfb + (size_t)b * 2112;
    if (t < 9) o[t] = f2bf(battle_x[b * 9 + t]);
    if (t < 21) o[2091 + t] = 0;
    for (int s = 0; s < 2; ++s) {
        const short* __restrict__ us = u + (size_t)(b * 2 + s) * 6 * 512;
        const int act = active_idx[b * 2 + s];
        if (t < 17) o[9 + s * 1041 + t] = f2bf(side_x[(b * 2 + s) * 17 + t]);
        for (int c = t; c < 512; c += 256) {
            float mx = bf2f(us[c]);
            #pragma unroll
            for (int uu = 1; uu < 6; ++uu) mx = fmaxf(mx, bf2f(us[uu * 512 + c]));
            o[9 + s * 1041 + 17 + c]       = us[act * 512 + c];
            o[9 + s * 1041 + 17 + 512 + c] = f2bf(mx);
        }
    }
}

// ---------------------------------------------------------------------------
// Move-head epilogue
// ---------------------------------------------------------------------------
__global__ __launch_bounds__(512) void k_epi_mo(
    const float* __restrict__ C_mo, size_t partStride, int nparts,
    const float* __restrict__ D_mv,
    const float* __restrict__ W1, const float* __restrict__ W2,
    const float* __restrict__ b2,
    const float* __restrict__ move_mask, const float* __restrict__ can_tera,
    float* __restrict__ out)
{
    __shared__ float red[8][8];
    const int b = blockIdx.x, t = threadIdx.x;
    float h = 0.f;
    for (int p = 0; p < nparts; ++p) h += C_mo[p * partStride + (size_t)b * 512 + t];
    const float wt = W1[(size_t)2219 * 512 + t];
    const float w2 = W2[t];
    float dm[4];
    #pragma unroll
    for (int m = 0; m < 4; ++m) dm[m] = D_mv[((size_t)b * 4 + m) * 512 + t];
    const int lane = t & 63, wid = t >> 6;
    #pragma unroll
    for (int m = 0; m < 4; ++m) {
        #pragma unroll
        for (int tt = 0; tt < 2; ++tt) {
            float hv = fmaxf(h + dm[m] + (tt ? wt : 0.f), 0.f);
            float v = hv * w2;
            #pragma unroll
            for (int off = 32; off > 0; off >>= 1) v += __shfl_down(v, off);
            if (lane == 0) red[m * 2 + tt][wid] = v;
        }
    }
    __syncthreads();
    if (t < 8) {
        float s = 0.f;
        #pragma unroll
        for (int ww = 0; ww < 8; ++ww) s += red[t][ww];
        s += b2[0];
        const int m = t >> 1, tt = t & 1;
        const float ok = move_mask[b * 4 + m] * (tt ? can_tera[b] : 1.f);
        out[b * 14 + t] = (ok > 0.f) ? s : NEG_BIG;
    }
}

// ---------------------------------------------------------------------------
// Switch-head epilogue
// ---------------------------------------------------------------------------
__global__ __launch_bounds__(512) void k_epi_sw(
    const float* __restrict__ C_so, size_t partStride, int nparts,
    const float* __restrict__ D_sw,
    const float* __restrict__ W2, const float* __restrict__ b2,
    const float* __restrict__ switch_mask, float* __restrict__ out)
{
    __shared__ float red[6][8];
    const int b = blockIdx.x, t = threadIdx.x;
    float h = 0.f;
    for (int p = 0; p < nparts; ++p) h += C_so[p * partStride + (size_t)b * 512 + t];
    const float w2 = W2[t];
    const int lane = t & 63, wid = t >> 6;
    #pragma unroll
    for (int j = 0; j < 6; ++j) {
        float hv = fmaxf(h + D_sw[((size_t)b * 6 + j) * 512 + t], 0.f);
        float v = hv * w2;
        #pragma unroll
        for (int off = 32; off > 0; off >>= 1) v += __shfl_down(v, off);
        if (lane == 0) red[j][wid] = v;
    }
    __syncthreads();
    if (t < 6) {
        float s = 0.f;
        #pragma unroll
        for (int ww = 0; ww < 8; ++ww) s += red[t][ww];
        s += b2[0];
        out[b * 14 + 8 + t] = (switch_mask[b * 6 + t] > 0.f) ? s : NEG_BIG;
    }
}

// ---------------------------------------------------------------------------
extern "C" void kernel_launch(void* const* d_in, const int* in_sizes, int n_in,
                              void* d_out, int out_size, void* d_ws, size_t ws_size,
                              hipStream_t stream) {
    const float* battle_x    = (const float*)d_in[0];
    const float* side_x      = (const float*)d_in[1];
    const float* user_x      = (const float*)d_in[2];
    const float* moveset     = (const float*)d_in[3];
    const float* movepool    = (const float*)d_in[4];
    const float* lookup      = (const float*)d_in[5];
    const float* lookup_mask = (const float*)d_in[6];
    const float* lastberry   = (const float*)d_in[7];
    const float* berry_mask  = (const float*)d_in[8];
    const float* items       = (const float*)d_in[9];
    const float* abilities   = (const float*)d_in[10];
    const float* types_x     = (const float*)d_in[11];
    const float* tera_types  = (const float*)d_in[12];
    const float* opt_moves   = (const float*)d_in[13];
    const float* move_mask   = (const float*)d_in[14];
    const float* can_tera    = (const float*)d_in[15];
    const float* switch_mask = (const float*)d_in[16];
    const float* W_item = (const float*)d_in[17];
    const float* b_item = (const float*)d_in[18];
    const float* W_ab   = (const float*)d_in[19];
    const float* b_ab   = (const float*)d_in[20];
    const float* W_ms   = (const float*)d_in[21];
    const float* b_ms   = (const float*)d_in[22];
    const float* W_user = (const float*)d_in[23];
    const float* b_user = (const float*)d_in[24];
    const float* W_mo1  = (const float*)d_in[25];
    const float* b_mo1  = (const float*)d_in[26];
    const float* W_mo2  = (const float*)d_in[27];
    const float* b_mo2  = (const float*)d_in[28];
    const float* W_so1  = (const float*)d_in[29];
    const float* b_so1  = (const float*)d_in[30];
    const float* W_so2  = (const float*)d_in[31];
    const float* b_so2  = (const float*)d_in[32];
    const int* active_idx = (const int*)d_in[33];
    const int* switch_idx = (const int*)d_in[34];
    float* out = (float*)d_out;

    char* base = (char*)d_ws;
    size_t off = 0;
    short* u_in = (short*)(base + off); off += (size_t)6144 * 1312 * 2;
    short* u    = (short*)(base + off); off += (size_t)6144 * 512 * 2;
    short* bfb  = (short*)(base + off); off += (size_t)512 * 2112 * 2;
    float* C_mo = (float*)(base + off); off += (size_t)6 * 512 * 512 * 4;
    float* C_so = (float*)(base + off); off += (size_t)6 * 512 * 512 * 4;
    float* D_mv = (float*)(base + off); off += (size_t)2048 * 512 * 4;
    float* D_sw = (float*)(base + off); off += (size_t)3072 * 512 * 4;
    short* Wt_pre  = (short*)(base + off); off += (size_t)128 * 1056 * 2;
    short* Wt_user = (short*)(base + off); off += (size_t)512 * 1312 * 2;
    short* Wt_mo   = (short*)(base + off); off += (size_t)512 * 2112 * 2;
    short* Wt_so   = (short*)(base + off); off += (size_t)512 * 2112 * 2;
    short* Wt_mv   = (short*)(base + off); off += (size_t)512 * 128 * 2;
    short* Wt_sw   = (short*)(base + off); off += (size_t)512 * 512 * 2;

    // --- weight prep (one dispatch) ---
    k_wprep_all<<<3220, 256, 0, stream>>>(W_ms, W_item, W_ab, W_user, W_mo1, W_so1,
                                          Wt_pre, Wt_user, Wt_mo, Wt_mv, Wt_so, Wt_sw);

    // --- pre-layer fused GEMM -> u_in (bf16) ---
    k_pre_gemm<<<3072, 256, 0, stream>>>(moveset, movepool, lookup, items, lastberry,
                                         abilities, lookup_mask, berry_mask,
                                         user_x, types_x, tera_types,
                                         Wt_pre, b_ms, b_item, b_ab, u_in);
    // --- u = relu(u_in @ W_user + b_user) (bf16 out) ---
    k_gemm<0, true, true, true, true><<<dim3(192, 4, 1), 256, 0, stream>>>(
        u_in, 1312, nullptr, nullptr, Wt_user, 1312, b_user, u, 0, 41);
    // --- battle_full (bf16) ---
    k_battle<<<BATCH, 256, 0, stream>>>(battle_x, side_x, u, active_idx, bfb);
    // --- heads ---
    k_gemm<0, true, false, true, false><<<dim3(16, 4, 6), 256, 0, stream>>>(
        bfb, 2112, nullptr, nullptr, Wt_mo, 2112, b_mo1, C_mo, (size_t)512 * 512, 11);
    k_gemm<0, false, false, false, false><<<dim3(64, 4, 1), 256, 0, stream>>>(
        opt_moves, 128, nullptr, nullptr, Wt_mv, 128, nullptr, D_mv, 0, 4);
    k_gemm<0, true, false, true, false><<<dim3(16, 4, 6), 256, 0, stream>>>(
        bfb, 2112, nullptr, nullptr, Wt_so, 2112, b_so1, C_so, (size_t)512 * 512, 11);
    k_gemm<1, true, false, false, false><<<dim3(96, 4, 1), 256, 0, stream>>>(
        nullptr, 0, u, switch_idx, Wt_sw, 512, nullptr, D_sw, 0, 16);
    // --- epilogues ---
    k_epi_mo<<<BATCH, 512, 0, stream>>>(C_mo, (size_t)512 * 512, 6, D_mv, W_mo1,
                                        W_mo2, b_mo2, move_mask, can_tera, out);
    k_epi_sw<<<BATCH, 512, 0, stream>>>(C_so, (size_t)512 * 512, 6, D_sw,
                                        W_so2, b_so2, switch_mask, out);
}